// Round 14
// baseline (978.821 us; speedup 1.0000x reference)
//
#include <hip/hip_runtime.h>
#include <hip/hip_bf16.h>

#define NB 64
#define NS 512
#define NV 1000
#define NF 64
#define NH 256

typedef short bf16x8 __attribute__((ext_vector_type(8)));
typedef float f32x4 __attribute__((ext_vector_type(4)));

__device__ __forceinline__ float bf2f(unsigned int u16bits){
    union { unsigned int i; float f; } v;
    v.i = (u16bits & 0xffffu) << 16;
    return v.f;
}

__device__ __forceinline__ float tanh_fast(float x){
    float e = __builtin_amdgcn_exp2f(x * 2.8853900817779268f);
    return 1.f - 2.f * __builtin_amdgcn_rcpf(e + 1.f);
}

__device__ __forceinline__ bool detect_f32(const void* probe){
    const unsigned short* p = (const unsigned short*)probe;
    bool bad = false; float mx = 0.f;
#pragma unroll
    for (int j = 0; j < 64; ++j){
        float v = fabsf(bf2f(p[j]));
        bad = bad || !(v == v);
        mx = fmaxf(mx, v);
    }
    return bad || (mx > 100.f);
}

// ---------------------------------------------------------------------------
// K0: canonicalize all 11 float inputs into bf16 — ONE launch.
// ---------------------------------------------------------------------------
struct ConvArgs { const void* src[11]; __hip_bfloat16* dst[11]; int n[11]; };

__global__ void k_conv_all(ConvArgs a, const void* __restrict__ probe){
    const int seg = blockIdx.y;
    const int n = a.n[seg];
    int i = blockIdx.x * 256 + threadIdx.x;
    if (i >= n) return;
    const bool f32in = detect_f32(probe);
    const int stride = gridDim.x * 256;
    __hip_bfloat16* dst = a.dst[seg];
    if (f32in){
        const float* s = (const float*)a.src[seg];
        for (; i < n; i += stride) dst[i] = __float2bfloat16(s[i]);
    } else {
        const unsigned short* s = (const unsigned short*)a.src[seg];
        for (; i < n; i += stride) dst[i] = __float2bfloat16(bf2f(s[i]));
    }
}

// ---------------------------------------------------------------------------
// K1: pre0[v][h] = dot(features[v,:], W_ih0[h,:]) + b_ih0[h] + b_hh0[h] (bf16)
// ---------------------------------------------------------------------------
__global__ void k_pre0(const __hip_bfloat16* __restrict__ feats,
                       const __hip_bfloat16* __restrict__ Wih,
                       const __hip_bfloat16* __restrict__ bih,
                       const __hip_bfloat16* __restrict__ bhh,
                       __hip_bfloat16* __restrict__ pre0){
    const int v = blockIdx.x, h = threadIdx.x;
    __shared__ __align__(16) float fsh[NF];
    if (h < NF) fsh[h] = __bfloat162float(feats[v*NF + h]);
    __syncthreads();
    const uint4* wr = reinterpret_cast<const uint4*>(Wih + h*NF);
    float acc = __bfloat162float(bih[h]) + __bfloat162float(bhh[h]);
#pragma unroll
    for (int j = 0; j < 8; ++j){
        uint4 q = wr[j];
        const float* hf = &fsh[j*8];
        acc += hf[0]*bf2f(q.x) + hf[1]*bf2f(q.x>>16)
             + hf[2]*bf2f(q.y) + hf[3]*bf2f(q.y>>16)
             + hf[4]*bf2f(q.z) + hf[5]*bf2f(q.z>>16)
             + hf[6]*bf2f(q.w) + hf[7]*bf2f(q.w>>16);
    }
    pre0[v*NH + h] = __float2bfloat16(acc);
}

// ---------------------------------------------------------------------------
// K2: FUSED 2-layer RNN — 4-WAVE variant (round-13 diagnosis: 8-wave version
// is LDS-BW-bound: 192 ds_read_b128/step/CU ≈ 2300cyc of the 2700cyc step;
// LDS traffic scales with wave count since each wave reads the full H tile).
// 4 WGs x 256 threads (4 waves, 1/SIMD), 16 batch rows/WG, 64 cols/wave:
// LDS reads halve (96/step). 3 weight sets x [4][8] = 384 pinned VGPRs
// (512-reg budget at 1 wave/SIMD; round-8 pin pattern; FETCH is the verdict).
// Step: [early: h1[s-1] frags] A: h0 matvec->tanh->LDS; BAR; C: Whh1@h1[s-1]
// from regs; B: Wih1@h0[s] (ds_reads under C's MFMAs); tanh->LDS+HBM; BAR.
// ---------------------------------------------------------------------------
#define BAR() do { asm volatile("s_waitcnt lgkmcnt(0)" ::: "memory");  \
                   __builtin_amdgcn_s_barrier();                        \
                   asm volatile("" ::: "memory"); } while (0)

#define PHASE(WF, BOFF, ACC)                                                      \
  _Pragma("unroll") for (int kc = 0; kc < 2; ++kc){                               \
    bf16x8 hfa[4];                                                                \
    _Pragma("unroll") for (int j = 0; j < 4; ++j)                                 \
      hfa[j] = *reinterpret_cast<const bf16x8*>(                                  \
          ldsb + (BOFF) + roffb + (kc*4 + j)*1024);                               \
    _Pragma("unroll") for (int j = 0; j < 4; ++j){                                \
      _Pragma("unroll") for (int nt = 0; nt < 4; ++nt)                            \
        ACC[nt] = __builtin_amdgcn_mfma_f32_16x16x32_bf16(                        \
            WF[nt][kc*4+j], hfa[j], ACC[nt], 0,0,0);                              \
    }                                                                             \
  }

#define PHASER(WF, HARR, ACC)                                                     \
  _Pragma("unroll") for (int ks = 0; ks < 8; ++ks){                               \
    _Pragma("unroll") for (int nt = 0; nt < 4; ++nt)                              \
      ACC[nt] = __builtin_amdgcn_mfma_f32_16x16x32_bf16(                          \
          WF[nt][ks], HARR[ks], ACC[nt], 0,0,0);                                  \
  }

#define TANH_PACK_STORE(ACC, WOFF, GSTORE, SPAR)                                  \
  _Pragma("unroll") for (int nt = 0; nt < 4; ++nt){                               \
    float t0 = tanh_fast(ACC[nt][0]), t1 = tanh_fast(ACC[nt][1]);                 \
    float t2 = tanh_fast(ACC[nt][2]), t3 = tanh_fast(ACC[nt][3]);                 \
    unsigned plo, phi;                                                            \
    asm("v_cvt_pk_bf16_f32 %0, %1, %2" : "=v"(plo) : "v"(t0), "v"(t1));           \
    asm("v_cvt_pk_bf16_f32 %0, %1, %2" : "=v"(phi) : "v"(t2), "v"(t3));           \
    uint2 p; p.x = plo; p.y = phi;                                                \
    *reinterpret_cast<uint2*>(ldsb + (WOFF) + woffb + nt*512) = p;                \
    if (GSTORE) *reinterpret_cast<uint2*>(hop + (SPAR)*NH + nt*16) = p;           \
  }

#define STEP(R0, W0, R1, W1, XS, IREG, SPAR)                                      \
  do {                                                                            \
    bf16x8 hC[8];                                                                 \
    _Pragma("unroll") for (int ks = 0; ks < 8; ++ks)                              \
      hC[ks] = *reinterpret_cast<const bf16x8*>(ldsb + (R1) + roffb + ks*1024);   \
    f32x4 acc0[4];                                                                \
    _Pragma("unroll") for (int nt = 0; nt < 4; ++nt)                              \
      _Pragma("unroll") for (int r = 0; r < 4; ++r)                               \
        acc0[nt][r] = bf2f(((const unsigned short*)&XS[nt])[r]);                  \
    { const unsigned short* gb = pre0b + (size_t)IREG*NH + cq;                    \
      _Pragma("unroll") for (int nt = 0; nt < 4; ++nt)                            \
        XS[nt] = *reinterpret_cast<const ushort4*>(gb + nt*16);                   \
      int sn = s + (SPAR) + 4; sn = (sn < NS) ? sn : NS - 1;                      \
      IREG = batch_g[sn]; }                                                       \
    PHASE(wf0, R0, acc0);                                                         \
    TANH_PACK_STORE(acc0, W0, 0, SPAR);                                           \
    BAR();                                                                        \
    f32x4 acc1[4]; acc1[0] = biasv[0]; acc1[1] = biasv[1];                        \
    acc1[2] = biasv[2]; acc1[3] = biasv[3];                                       \
    PHASER(wf1, hC, acc1);                                                        \
    PHASE(wfG, W0, acc1);                                                         \
    TANH_PACK_STORE(acc1, W1, 1, SPAR);                                           \
    BAR();                                                                        \
  } while (0)

__global__ __launch_bounds__(256, 1) void k_rnn_fused(
        const int* __restrict__ batch,
        const unsigned short* __restrict__ pre0b,
        const __hip_bfloat16* __restrict__ Whh0,
        const __hip_bfloat16* __restrict__ Wih1,
        const __hip_bfloat16* __restrict__ Whh1,
        const __hip_bfloat16* __restrict__ bih1,
        const __hip_bfloat16* __restrict__ bhh1,
        __hip_bfloat16* __restrict__ hout){
    const int l  = threadIdx.x & 63;
    const int w  = threadIdx.x >> 6;   // 0..3
    const int b0 = blockIdx.x * 16;
    const int lr = l & 15;
    const int kq = l >> 4;
    const int c0 = w * 64;             // 64 cols/wave
    const int cq = c0 + kq*4;

    // 3 weight A-frag sets, 384 VGPRs, loaded once, pinned.
    bf16x8 wf0[4][8], wfG[4][8], wf1[4][8];
#pragma unroll
    for (int nt = 0; nt < 4; ++nt)
#pragma unroll
        for (int ks = 0; ks < 8; ++ks){
            const size_t o = (size_t)(c0 + nt*16 + lr)*NH + ks*32 + kq*8;
            wf0[nt][ks] = *reinterpret_cast<const bf16x8*>(Whh0 + o);
            wfG[nt][ks] = *reinterpret_cast<const bf16x8*>(Wih1 + o);
            wf1[nt][ks] = *reinterpret_cast<const bf16x8*>(Whh1 + o);
            asm volatile("" : "+v"(wf0[nt][ks]));
            asm volatile("" : "+v"(wfG[nt][ks]));
            asm volatile("" : "+v"(wf1[nt][ks]));
        }

    f32x4 biasv[4];
#pragma unroll
    for (int nt = 0; nt < 4; ++nt)
#pragma unroll
        for (int r = 0; r < 4; ++r){
            int c = cq + nt*16 + r;
            biasv[nt][r] = __bfloat162float(bih1[c]) + __bfloat162float(bhh1[c]);
        }

    // LDS: h0 dbuf @0/8192, h1 dbuf @16384/24576 ([k8][row]*16B chunks)
    __shared__ __align__(16) char lds_all[32768];
    char* ldsb = lds_all;
    *reinterpret_cast<uint4*>(ldsb + threadIdx.x*16)          = uint4{0,0,0,0};
    *reinterpret_cast<uint4*>(ldsb + 4096  + threadIdx.x*16)  = uint4{0,0,0,0};
    *reinterpret_cast<uint4*>(ldsb + 16384 + threadIdx.x*16)  = uint4{0,0,0,0};
    *reinterpret_cast<uint4*>(ldsb + 20480 + threadIdx.x*16)  = uint4{0,0,0,0};

    const int roffb = kq*256 + lr*16;
    const int woffb = (cq >> 3)*256 + lr*16 + (cq & 7)*2;

    const int* batch_g = batch + (size_t)(b0 + lr)*NS;
    __hip_bfloat16* hop = hout + ((size_t)(b0+lr)*NS)*NH + cq;

    ushort4 xA[4], xB[4]; int iA, iB;
    {
        int j0 = batch_g[0], j1 = batch_g[1];
        const unsigned short* g0 = pre0b + (size_t)j0*NH + cq;
        const unsigned short* g1 = pre0b + (size_t)j1*NH + cq;
#pragma unroll
        for (int nt = 0; nt < 4; ++nt){
            xA[nt] = *reinterpret_cast<const ushort4*>(g0 + nt*16);
            xB[nt] = *reinterpret_cast<const ushort4*>(g1 + nt*16);
        }
        iA = batch_g[2]; iB = batch_g[3];
    }
    __syncthreads();

    for (int s = 0; s < NS; s += 2){
        STEP(0,    8192, 16384, 24576, xA, iA, 0);
        STEP(8192, 0,    24576, 16384, xB, iB, 1);
        hop += 2*NH;
    }
}

// ---------------------------------------------------------------------------
// K3: output GEMM, 256-row macro-tile per WG (round-13, unchanged).
// ---------------------------------------------------------------------------
template<int N>
__global__ __launch_bounds__(256, 2) void k_gemm_big(
        const __hip_bfloat16* __restrict__ A,
        const __hip_bfloat16* __restrict__ W,
        const __hip_bfloat16* __restrict__ bias,
        void* __restrict__ Cout, int ldc,
        const void* __restrict__ probe){
    const bool f32out = detect_f32(probe);
    const int m0 = blockIdx.x * 256;
    const int n0 = blockIdx.y * 64;
    const int wv = threadIdx.x >> 6;
    const int l  = threadIdx.x & 63;
    const int lr = l & 15;
    const int kb = (l >> 4) * 8;

    bf16x8 wfr[4][8];
#pragma unroll
    for (int nt = 0; nt < 4; ++nt){
        int ncol = n0 + nt*16 + lr;
        int nc = (ncol < N) ? ncol : (N-1);
#pragma unroll
        for (int ks = 0; ks < 8; ++ks){
            wfr[nt][ks] = *reinterpret_cast<const bf16x8*>(
                W + (size_t)nc*NH + ks*32 + kb);
            asm volatile("" : "+v"(wfr[nt][ks]));
        }
    }

    float bsum[4];
#pragma unroll
    for (int nt = 0; nt < 4; ++nt){
        int ncol = n0 + nt*16 + lr;
        bsum[nt] = (ncol < N) ? __bfloat162float(bias[ncol]) : 0.f;
    }

#pragma unroll
    for (int mt = 0; mt < 4; ++mt){
        const int mrow = m0 + mt*64 + wv*16 + lr;
        bf16x8 af[8];
#pragma unroll
        for (int ks = 0; ks < 8; ++ks)
            af[ks] = *reinterpret_cast<const bf16x8*>(
                A + (size_t)mrow*NH + ks*32 + kb);
        f32x4 acc[4] = {};
#pragma unroll
        for (int ks = 0; ks < 8; ++ks){
#pragma unroll
            for (int nt = 0; nt < 4; ++nt)
                acc[nt] = __builtin_amdgcn_mfma_f32_16x16x32_bf16(
                    af[ks], wfr[nt][ks], acc[nt], 0, 0, 0);
        }
#pragma unroll
        for (int nt = 0; nt < 4; ++nt){
            int ncol = n0 + nt*16 + lr;
            if (ncol >= N) continue;
#pragma unroll
            for (int r = 0; r < 4; ++r){
                int row = m0 + mt*64 + wv*16 + (l>>4)*4 + r;
                float val = acc[nt][r] + bsum[nt];
                if (f32out) ((float*)Cout)[(size_t)row*ldc + ncol] = val;
                else        ((__hip_bfloat16*)Cout)[(size_t)row*ldc + ncol] = __float2bfloat16(val);
            }
        }
    }
}

// ---------------------------------------------------------------------------
extern "C" void kernel_launch(void* const* d_in, const int* in_sizes, int n_in,
                              void* d_out, int out_size, void* d_ws, size_t ws_size,
                              hipStream_t stream){
    const int* batch = (const int*)d_in[0];
    const void* probe = d_in[3];  // raw W_hh0 for dtype detection

    char* ws = (char*)d_ws;
    size_t off = 0;
    auto give = [&](size_t bytes)->char*{
        char* p = ws + off; off = (off + bytes + 511) & ~(size_t)511; return p;
    };
    __hip_bfloat16* cFeats = (__hip_bfloat16*)give(2*NV*NF);
    __hip_bfloat16* cWih0  = (__hip_bfloat16*)give(2*NH*NF);
    __hip_bfloat16* cWhh0  = (__hip_bfloat16*)give(2*NH*NH);
    __hip_bfloat16* cBih0  = (__hip_bfloat16*)give(2*NH);
    __hip_bfloat16* cBhh0  = (__hip_bfloat16*)give(2*NH);
    __hip_bfloat16* cWih1  = (__hip_bfloat16*)give(2*NH*NH);
    __hip_bfloat16* cWhh1  = (__hip_bfloat16*)give(2*NH*NH);
    __hip_bfloat16* cBih1  = (__hip_bfloat16*)give(2*NH);
    __hip_bfloat16* cBhh1  = (__hip_bfloat16*)give(2*NH);
    __hip_bfloat16* cWout  = (__hip_bfloat16*)give(2*NV*NH);
    __hip_bfloat16* cBout  = (__hip_bfloat16*)give(2*NV);
    __hip_bfloat16* pre0b  = (__hip_bfloat16*)give(2*NV*NH + 64);
    __hip_bfloat16* hbuf   = (__hip_bfloat16*)give(2*(size_t)NB*NS*NH);

    ConvArgs ca;
    const void* srcs[11] = { d_in[1], d_in[2], d_in[3], d_in[4], d_in[5], d_in[6],
                             d_in[7], d_in[8], d_in[9], d_in[10], d_in[11] };
    __hip_bfloat16* dsts[11] = { cFeats, cWih0, cWhh0, cBih0, cBhh0, cWih1,
                                 cWhh1, cBih1, cBhh1, cWout, cBout };
    int ns[11] = { NV*NF, NH*NF, NH*NH, NH, NH, NH*NH, NH*NH, NH, NH, NV*NH, NV };
    for (int i = 0; i < 11; ++i){ ca.src[i] = srcs[i]; ca.dst[i] = dsts[i]; ca.n[i] = ns[i]; }
    k_conv_all<<<dim3(64, 11), dim3(256), 0, stream>>>(ca, probe);

    k_pre0<<<dim3(NV), dim3(256), 0, stream>>>(cFeats, cWih0, cBih0, cBhh0, pre0b);
    k_rnn_fused<<<dim3(NB/16), dim3(256), 0, stream>>>(
        batch, (const unsigned short*)pre0b, cWhh0, cWih1, cWhh1, cBih1, cBhh1, hbuf);
    k_gemm_big<NV><<<dim3((NB*NS)/256, 16), dim3(256), 0, stream>>>(
        hbuf, cWout, cBout, d_out, NV, probe);
}

// Round 15
// 756.227 us; speedup vs baseline: 1.2943x; 1.2943x over previous
//
#include <hip/hip_runtime.h>
#include <hip/hip_bf16.h>

#define NB 64
#define NS 512
#define NV 1000
#define NF 64
#define NH 256

typedef short bf16x8 __attribute__((ext_vector_type(8)));
typedef float f32x4 __attribute__((ext_vector_type(4)));

__device__ __forceinline__ float bf2f(unsigned int u16bits){
    union { unsigned int i; float f; } v;
    v.i = (u16bits & 0xffffu) << 16;
    return v.f;
}

__device__ __forceinline__ float tanh_fast(float x){
    float e = __builtin_amdgcn_exp2f(x * 2.8853900817779268f);
    return 1.f - 2.f * __builtin_amdgcn_rcpf(e + 1.f);
}

__device__ __forceinline__ bool detect_f32(const void* probe){
    const unsigned short* p = (const unsigned short*)probe;
    bool bad = false; float mx = 0.f;
#pragma unroll
    for (int j = 0; j < 64; ++j){
        float v = fabsf(bf2f(p[j]));
        bad = bad || !(v == v);
        mx = fmaxf(mx, v);
    }
    return bad || (mx > 100.f);
}

// ---------------------------------------------------------------------------
// K0: canonicalize all 11 float inputs into bf16 — ONE launch.
// ---------------------------------------------------------------------------
struct ConvArgs { const void* src[11]; __hip_bfloat16* dst[11]; int n[11]; };

__global__ void k_conv_all(ConvArgs a, const void* __restrict__ probe){
    const int seg = blockIdx.y;
    const int n = a.n[seg];
    int i = blockIdx.x * 256 + threadIdx.x;
    if (i >= n) return;
    const bool f32in = detect_f32(probe);
    const int stride = gridDim.x * 256;
    __hip_bfloat16* dst = a.dst[seg];
    if (f32in){
        const float* s = (const float*)a.src[seg];
        for (; i < n; i += stride) dst[i] = __float2bfloat16(s[i]);
    } else {
        const unsigned short* s = (const unsigned short*)a.src[seg];
        for (; i < n; i += stride) dst[i] = __float2bfloat16(bf2f(s[i]));
    }
}

// ---------------------------------------------------------------------------
// K1: pre0[v][h] = dot(features[v,:], W_ih0[h,:]) + b_ih0[h] + b_hh0[h] (bf16)
// ---------------------------------------------------------------------------
__global__ void k_pre0(const __hip_bfloat16* __restrict__ feats,
                       const __hip_bfloat16* __restrict__ Wih,
                       const __hip_bfloat16* __restrict__ bih,
                       const __hip_bfloat16* __restrict__ bhh,
                       __hip_bfloat16* __restrict__ pre0){
    const int v = blockIdx.x, h = threadIdx.x;
    __shared__ __align__(16) float fsh[NF];
    if (h < NF) fsh[h] = __bfloat162float(feats[v*NF + h]);
    __syncthreads();
    const uint4* wr = reinterpret_cast<const uint4*>(Wih + h*NF);
    float acc = __bfloat162float(bih[h]) + __bfloat162float(bhh[h]);
#pragma unroll
    for (int j = 0; j < 8; ++j){
        uint4 q = wr[j];
        const float* hf = &fsh[j*8];
        acc += hf[0]*bf2f(q.x) + hf[1]*bf2f(q.x>>16)
             + hf[2]*bf2f(q.y) + hf[3]*bf2f(q.y>>16)
             + hf[4]*bf2f(q.z) + hf[5]*bf2f(q.z>>16)
             + hf[6]*bf2f(q.w) + hf[7]*bf2f(q.w>>16);
    }
    pre0[v*NH + h] = __float2bfloat16(acc);
}

// ---------------------------------------------------------------------------
// K2: FUSED 2-layer RNN, LAYER-PIPELINED (round-14 diagnosis: 8-wave round-12
// kernel is LDS-BW-bound at 24 ds_read_b128/thread/step; 4-wave variant spills).
// Iteration t computes BOTH  h0[t]   = tanh(xp0[t]   + Whh0@h0[t-1])
//                  and       h1[t-1] = tanh(bias + Wih1@h0[t-1] + Whh1@h1[t-2])
// so phases A and B SHARE one h0[t-1] fragment read (24 -> 16 reads/thread),
// and all operands are from previous iterations -> ONE barrier/step (was 2).
// Ring slots (verified disjoint): h0 R(t-1)&1 W t&1; h1 R(t-2)&1 W(t-1)&1.
// Guards: h1 store only for 0 <= s < NS (s = t-1); tail h0 values unused.
// 4 WGs x 512 thr (8 waves, 2/SIMD), 16 rows/WG, 32 cols/wave; weights
// pinned once (AGPR-parked per round-12: VGPR_Count 124, FETCH 1.85MB).
// ---------------------------------------------------------------------------
#define BAR() do { asm volatile("s_waitcnt lgkmcnt(0)" ::: "memory");  \
                   __builtin_amdgcn_s_barrier();                        \
                   asm volatile("" ::: "memory"); } while (0)

#define MFMA16(A, B, C) __builtin_amdgcn_mfma_f32_16x16x32_bf16(A, B, C, 0, 0, 0)

#define STEP(RH0, WH0, RH1, WH1, XS, IREG, S)                                     \
  do {                                                                            \
    bf16x8 hC[8];   /* h1[t-2] */                                                 \
    _Pragma("unroll") for (int ks = 0; ks < 8; ++ks)                              \
      hC[ks] = *reinterpret_cast<const bf16x8*>(ldsb + (RH1) + roffb + ks*1024);  \
    f32x4 acc0[2];                                                                \
    _Pragma("unroll") for (int nt = 0; nt < 2; ++nt)                              \
      _Pragma("unroll") for (int r = 0; r < 4; ++r)                               \
        acc0[nt][r] = bf2f(((const unsigned short*)&XS[nt])[r]);                  \
    { const unsigned short* gb = pre0b + (size_t)IREG*NH + cq;                    \
      XS[0] = *reinterpret_cast<const ushort4*>(gb);                              \
      XS[1] = *reinterpret_cast<const ushort4*>(gb + 16);                         \
      int sn = (S) + 5; sn = (sn < NS) ? sn : NS - 1;                             \
      IREG = batch_g[sn]; }                                                       \
    f32x4 acc1[2]; acc1[0] = biasv[0]; acc1[1] = biasv[1];                        \
    _Pragma("unroll") for (int kc = 0; kc < 2; ++kc){                             \
      bf16x8 hfa[4];  /* h0[t-1], SHARED by A and B chains */                     \
      _Pragma("unroll") for (int j = 0; j < 4; ++j)                               \
        hfa[j] = *reinterpret_cast<const bf16x8*>(                                \
            ldsb + (RH0) + roffb + (kc*4 + j)*1024);                              \
      _Pragma("unroll") for (int j = 0; j < 4; ++j){                              \
        acc0[0] = MFMA16(wf0[0][kc*4+j], hfa[j], acc0[0]);                        \
        acc0[1] = MFMA16(wf0[1][kc*4+j], hfa[j], acc0[1]);                        \
        acc1[0] = MFMA16(wfG[0][kc*4+j], hfa[j], acc1[0]);                        \
        acc1[1] = MFMA16(wfG[1][kc*4+j], hfa[j], acc1[1]);                        \
      }                                                                           \
    }                                                                             \
    _Pragma("unroll") for (int ks = 0; ks < 8; ++ks){                             \
      acc1[0] = MFMA16(wf1[0][ks], hC[ks], acc1[0]);                              \
      acc1[1] = MFMA16(wf1[1][ks], hC[ks], acc1[1]);                              \
    }                                                                             \
    _Pragma("unroll") for (int nt = 0; nt < 2; ++nt){   /* h0[t] -> LDS */        \
      float t0 = tanh_fast(acc0[nt][0]), t1 = tanh_fast(acc0[nt][1]);             \
      float t2 = tanh_fast(acc0[nt][2]), t3 = tanh_fast(acc0[nt][3]);             \
      unsigned plo, phi;                                                          \
      asm("v_cvt_pk_bf16_f32 %0, %1, %2" : "=v"(plo) : "v"(t0), "v"(t1));         \
      asm("v_cvt_pk_bf16_f32 %0, %1, %2" : "=v"(phi) : "v"(t2), "v"(t3));         \
      uint2 p; p.x = plo; p.y = phi;                                              \
      *reinterpret_cast<uint2*>(ldsb + (WH0) + woffb + nt*512) = p;               \
    }                                                                             \
    if ((unsigned)(S) < NS){   /* h1[s] -> LDS + HBM, s = t-1 */                  \
      _Pragma("unroll") for (int nt = 0; nt < 2; ++nt){                           \
        float t0 = tanh_fast(acc1[nt][0]), t1 = tanh_fast(acc1[nt][1]);           \
        float t2 = tanh_fast(acc1[nt][2]), t3 = tanh_fast(acc1[nt][3]);           \
        unsigned plo, phi;                                                        \
        asm("v_cvt_pk_bf16_f32 %0, %1, %2" : "=v"(plo) : "v"(t0), "v"(t1));       \
        asm("v_cvt_pk_bf16_f32 %0, %1, %2" : "=v"(phi) : "v"(t2), "v"(t3));       \
        uint2 p; p.x = plo; p.y = phi;                                            \
        *reinterpret_cast<uint2*>(ldsb + (WH1) + woffb + nt*512) = p;             \
        *reinterpret_cast<uint2*>(hob + ((size_t)(S) << 8) + nt*16) = p;          \
      }                                                                           \
    }                                                                             \
    BAR();                                                                        \
  } while (0)

__global__ __launch_bounds__(512, 2) void k_rnn_fused(
        const int* __restrict__ batch,
        const unsigned short* __restrict__ pre0b,
        const __hip_bfloat16* __restrict__ Whh0,
        const __hip_bfloat16* __restrict__ Wih1,
        const __hip_bfloat16* __restrict__ Whh1,
        const __hip_bfloat16* __restrict__ bih1,
        const __hip_bfloat16* __restrict__ bhh1,
        __hip_bfloat16* __restrict__ hout){
    const int l  = threadIdx.x & 63;
    const int w  = threadIdx.x >> 6;   // 0..7
    const int b0 = blockIdx.x * 16;
    const int lr = l & 15;
    const int kq = l >> 4;
    const int c0 = w * 32;
    const int cq = c0 + kq*4;

    // 3 weight A-frag sets: [c0+nt*16+lr][ks*32+kq*8 ..+8] — loaded once, pinned.
    bf16x8 wf0[2][8], wfG[2][8], wf1[2][8];
#pragma unroll
    for (int nt = 0; nt < 2; ++nt)
#pragma unroll
        for (int ks = 0; ks < 8; ++ks){
            const size_t o = (size_t)(c0 + nt*16 + lr)*NH + ks*32 + kq*8;
            wf0[nt][ks] = *reinterpret_cast<const bf16x8*>(Whh0 + o);
            wfG[nt][ks] = *reinterpret_cast<const bf16x8*>(Wih1 + o);
            wf1[nt][ks] = *reinterpret_cast<const bf16x8*>(Whh1 + o);
            asm volatile("" : "+v"(wf0[nt][ks]));
            asm volatile("" : "+v"(wfG[nt][ks]));
            asm volatile("" : "+v"(wf1[nt][ks]));
        }

    f32x4 biasv[2];
#pragma unroll
    for (int nt = 0; nt < 2; ++nt)
#pragma unroll
        for (int r = 0; r < 4; ++r){
            int c = cq + nt*16 + r;
            biasv[nt][r] = __bfloat162float(bih1[c]) + __bfloat162float(bhh1[c]);
        }

    // LDS: h0 slots @0/8192, h1 slots @16384/24576 ([k8][row]*16B chunks).
    // Zero ALL (t=0 reads h0 slot1; t=1 reads h1 slot1; t=0 reads h1 slot0).
    __shared__ __align__(16) char lds_all[32768];
    char* ldsb = lds_all;
    *reinterpret_cast<uint4*>(ldsb + threadIdx.x*16)          = uint4{0,0,0,0};
    *reinterpret_cast<uint4*>(ldsb + 8192  + threadIdx.x*16)  = uint4{0,0,0,0};
    *reinterpret_cast<uint4*>(ldsb + 16384 + threadIdx.x*16)  = uint4{0,0,0,0};
    *reinterpret_cast<uint4*>(ldsb + 24576 + threadIdx.x*16)  = uint4{0,0,0,0};

    const int roffb = kq*256 + lr*16;
    const int woffb = (cq >> 3)*256 + lr*16 + (cq & 7)*2;

    const int* batch_g = batch + (size_t)(b0 + lr)*NS;
    __hip_bfloat16* hob = hout + ((size_t)(b0+lr)*NS)*NH + cq;

    // depth-2 gather prefetch (xA even t, xB odd t), idx regs 4 ahead
    ushort4 xA[2], xB[2]; int iA, iB;
    {
        int j0 = batch_g[0], j1 = batch_g[1];
        const unsigned short* g0 = pre0b + (size_t)j0*NH + cq;
        const unsigned short* g1 = pre0b + (size_t)j1*NH + cq;
        xA[0] = *reinterpret_cast<const ushort4*>(g0);
        xA[1] = *reinterpret_cast<const ushort4*>(g0 + 16);
        xB[0] = *reinterpret_cast<const ushort4*>(g1);
        xB[1] = *reinterpret_cast<const ushort4*>(g1 + 16);
        iA = batch_g[2]; iB = batch_g[3];
    }
    __syncthreads();   // zeroed slots visible

    // 257 pairs cover t = 0..513; s = t-1 spans -1..512 (stores guarded to 0..511)
    for (int p = 0; p < 257; ++p){
        const int t = p*2;
        STEP(8192, 0,     16384, 24576, xA, iA, t-1);  // even t
        STEP(0,    8192,  24576, 16384, xB, iB, t);    // odd  t+1
    }
}

// ---------------------------------------------------------------------------
// K3: output GEMM, 256-row macro-tile per WG (round-13, unchanged).
// ---------------------------------------------------------------------------
template<int N>
__global__ __launch_bounds__(256, 2) void k_gemm_big(
        const __hip_bfloat16* __restrict__ A,
        const __hip_bfloat16* __restrict__ W,
        const __hip_bfloat16* __restrict__ bias,
        void* __restrict__ Cout, int ldc,
        const void* __restrict__ probe){
    const bool f32out = detect_f32(probe);
    const int m0 = blockIdx.x * 256;
    const int n0 = blockIdx.y * 64;
    const int wv = threadIdx.x >> 6;
    const int l  = threadIdx.x & 63;
    const int lr = l & 15;
    const int kb = (l >> 4) * 8;

    bf16x8 wfr[4][8];
#pragma unroll
    for (int nt = 0; nt < 4; ++nt){
        int ncol = n0 + nt*16 + lr;
        int nc = (ncol < N) ? ncol : (N-1);
#pragma unroll
        for (int ks = 0; ks < 8; ++ks){
            wfr[nt][ks] = *reinterpret_cast<const bf16x8*>(
                W + (size_t)nc*NH + ks*32 + kb);
            asm volatile("" : "+v"(wfr[nt][ks]));
        }
    }

    float bsum[4];
#pragma unroll
    for (int nt = 0; nt < 4; ++nt){
        int ncol = n0 + nt*16 + lr;
        bsum[nt] = (ncol < N) ? __bfloat162float(bias[ncol]) : 0.f;
    }

#pragma unroll
    for (int mt = 0; mt < 4; ++mt){
        const int mrow = m0 + mt*64 + wv*16 + lr;
        bf16x8 af[8];
#pragma unroll
        for (int ks = 0; ks < 8; ++ks)
            af[ks] = *reinterpret_cast<const bf16x8*>(
                A + (size_t)mrow*NH + ks*32 + kb);
        f32x4 acc[4] = {};
#pragma unroll
        for (int ks = 0; ks < 8; ++ks){
#pragma unroll
            for (int nt = 0; nt < 4; ++nt)
                acc[nt] = __builtin_amdgcn_mfma_f32_16x16x32_bf16(
                    af[ks], wfr[nt][ks], acc[nt], 0, 0, 0);
        }
#pragma unroll
        for (int nt = 0; nt < 4; ++nt){
            int ncol = n0 + nt*16 + lr;
            if (ncol >= N) continue;
#pragma unroll
            for (int r = 0; r < 4; ++r){
                int row = m0 + mt*64 + wv*16 + (l>>4)*4 + r;
                float val = acc[nt][r] + bsum[nt];
                if (f32out) ((float*)Cout)[(size_t)row*ldc + ncol] = val;
                else        ((__hip_bfloat16*)Cout)[(size_t)row*ldc + ncol] = __float2bfloat16(val);
            }
        }
    }
}

// ---------------------------------------------------------------------------
extern "C" void kernel_launch(void* const* d_in, const int* in_sizes, int n_in,
                              void* d_out, int out_size, void* d_ws, size_t ws_size,
                              hipStream_t stream){
    const int* batch = (const int*)d_in[0];
    const void* probe = d_in[3];  // raw W_hh0 for dtype detection

    char* ws = (char*)d_ws;
    size_t off = 0;
    auto give = [&](size_t bytes)->char*{
        char* p = ws + off; off = (off + bytes + 511) & ~(size_t)511; return p;
    };
    __hip_bfloat16* cFeats = (__hip_bfloat16*)give(2*NV*NF);
    __hip_bfloat16* cWih0  = (__hip_bfloat16*)give(2*NH*NF);
    __hip_bfloat16* cWhh0  = (__hip_bfloat16*)give(2*NH*NH);
    __hip_bfloat16* cBih0  = (__hip_bfloat16*)give(2*NH);
    __hip_bfloat16* cBhh0  = (__hip_bfloat16*)give(2*NH);
    __hip_bfloat16* cWih1  = (__hip_bfloat16*)give(2*NH*NH);
    __hip_bfloat16* cWhh1  = (__hip_bfloat16*)give(2*NH*NH);
    __hip_bfloat16* cBih1  = (__hip_bfloat16*)give(2*NH);
    __hip_bfloat16* cBhh1  = (__hip_bfloat16*)give(2*NH);
    __hip_bfloat16* cWout  = (__hip_bfloat16*)give(2*NV*NH);
    __hip_bfloat16* cBout  = (__hip_bfloat16*)give(2*NV);
    __hip_bfloat16* pre0b  = (__hip_bfloat16*)give(2*NV*NH + 64);
    __hip_bfloat16* hbuf   = (__hip_bfloat16*)give(2*(size_t)NB*NS*NH);

    ConvArgs ca;
    const void* srcs[11] = { d_in[1], d_in[2], d_in[3], d_in[4], d_in[5], d_in[6],
                             d_in[7], d_in[8], d_in[9], d_in[10], d_in[11] };
    __hip_bfloat16* dsts[11] = { cFeats, cWih0, cWhh0, cBih0, cBhh0, cWih1,
                                 cWhh1, cBih1, cBhh1, cWout, cBout };
    int ns[11] = { NV*NF, NH*NF, NH*NH, NH, NH, NH*NH, NH*NH, NH, NH, NV*NH, NV };
    for (int i = 0; i < 11; ++i){ ca.src[i] = srcs[i]; ca.dst[i] = dsts[i]; ca.n[i] = ns[i]; }
    k_conv_all<<<dim3(64, 11), dim3(256), 0, stream>>>(ca, probe);

    k_pre0<<<dim3(NV), dim3(256), 0, stream>>>(cFeats, cWih0, cBih0, cBhh0, pre0b);
    k_rnn_fused<<<dim3(NB/16), dim3(512), 0, stream>>>(
        batch, (const unsigned short*)pre0b, cWhh0, cWih1, cWhh1, cBih1, cBhh1, hbuf);
    k_gemm_big<NV><<<dim3((NB*NS)/256, 16), dim3(256), 0, stream>>>(
        hbuf, cWout, cBout, d_out, NV, probe);
}

// Round 16
// 747.964 us; speedup vs baseline: 1.3086x; 1.0110x over previous
//
#include <hip/hip_runtime.h>
#include <hip/hip_bf16.h>

#define NB 64
#define NS 512
#define NV 1000
#define NF 64
#define NH 256

typedef short bf16x8 __attribute__((ext_vector_type(8)));
typedef float f32x4 __attribute__((ext_vector_type(4)));

__device__ __forceinline__ float bf2f(unsigned int u16bits){
    union { unsigned int i; float f; } v;
    v.i = (u16bits & 0xffffu) << 16;
    return v.f;
}

__device__ __forceinline__ float tanh_fast(float x){
    float e = __builtin_amdgcn_exp2f(x * 2.8853900817779268f);
    return 1.f - 2.f * __builtin_amdgcn_rcpf(e + 1.f);
}

__device__ __forceinline__ bool detect_f32(const void* probe){
    const unsigned short* p = (const unsigned short*)probe;
    bool bad = false; float mx = 0.f;
#pragma unroll
    for (int j = 0; j < 64; ++j){
        float v = fabsf(bf2f(p[j]));
        bad = bad || !(v == v);
        mx = fmaxf(mx, v);
    }
    return bad || (mx > 100.f);
}

// ---------------------------------------------------------------------------
// K0: canonicalize all 11 float inputs into bf16 — ONE launch.
// ---------------------------------------------------------------------------
struct ConvArgs { const void* src[11]; __hip_bfloat16* dst[11]; int n[11]; };

__global__ void k_conv_all(ConvArgs a, const void* __restrict__ probe){
    const int seg = blockIdx.y;
    const int n = a.n[seg];
    int i = blockIdx.x * 256 + threadIdx.x;
    if (i >= n) return;
    const bool f32in = detect_f32(probe);
    const int stride = gridDim.x * 256;
    __hip_bfloat16* dst = a.dst[seg];
    if (f32in){
        const float* s = (const float*)a.src[seg];
        for (; i < n; i += stride) dst[i] = __float2bfloat16(s[i]);
    } else {
        const unsigned short* s = (const unsigned short*)a.src[seg];
        for (; i < n; i += stride) dst[i] = __float2bfloat16(bf2f(s[i]));
    }
}

// ---------------------------------------------------------------------------
// K1: pre0[v][h] = dot(features[v,:], W_ih0[h,:]) + b_ih0[h] + b_hh0[h] (bf16)
// ---------------------------------------------------------------------------
__global__ void k_pre0(const __hip_bfloat16* __restrict__ feats,
                       const __hip_bfloat16* __restrict__ Wih,
                       const __hip_bfloat16* __restrict__ bih,
                       const __hip_bfloat16* __restrict__ bhh,
                       __hip_bfloat16* __restrict__ pre0){
    const int v = blockIdx.x, h = threadIdx.x;
    __shared__ __align__(16) float fsh[NF];
    if (h < NF) fsh[h] = __bfloat162float(feats[v*NF + h]);
    __syncthreads();
    const uint4* wr = reinterpret_cast<const uint4*>(Wih + h*NF);
    float acc = __bfloat162float(bih[h]) + __bfloat162float(bhh[h]);
#pragma unroll
    for (int j = 0; j < 8; ++j){
        uint4 q = wr[j];
        const float* hf = &fsh[j*8];
        acc += hf[0]*bf2f(q.x) + hf[1]*bf2f(q.x>>16)
             + hf[2]*bf2f(q.y) + hf[3]*bf2f(q.y>>16)
             + hf[4]*bf2f(q.z) + hf[5]*bf2f(q.z>>16)
             + hf[6]*bf2f(q.w) + hf[7]*bf2f(q.w>>16);
    }
    pre0[v*NH + h] = __float2bfloat16(acc);
}

// ---------------------------------------------------------------------------
// K2: FUSED 2-layer RNN (round-12/13 passing structure, FROZEN — best known).
// 4 WGs x 512 threads (8 waves, 2/SIMD), 16 batch rows/WG, 32 cols/wave.
// Per step: [early: read h1[s-1] frags into regs] A: h0-matvec -> tanh ->
// h0 LDS; BAR; C: Whh1@h1[s-1] from PRELOADED regs; B: Wih1@h0[s] (ds_reads
// fly under C's MFMAs); tanh -> h1 LDS+HBM; BAR.
// At this structure's issue-bound floor: active-CU MfmaUtil ~48% + VALU ~46%.
// ---------------------------------------------------------------------------
#define BAR() do { asm volatile("s_waitcnt lgkmcnt(0)" ::: "memory");  \
                   __builtin_amdgcn_s_barrier();                        \
                   asm volatile("" ::: "memory"); } while (0)

#define PHASE(WF, BOFF, ACC)                                                      \
  _Pragma("unroll") for (int kc = 0; kc < 2; ++kc){                               \
    bf16x8 hfa[4];                                                                \
    _Pragma("unroll") for (int j = 0; j < 4; ++j)                                 \
      hfa[j] = *reinterpret_cast<const bf16x8*>(                                  \
          ldsb + (BOFF) + roffb + (kc*4 + j)*1024);                               \
    _Pragma("unroll") for (int j = 0; j < 4; ++j){                                \
      ACC[0] = __builtin_amdgcn_mfma_f32_16x16x32_bf16(WF[0][kc*4+j], hfa[j], ACC[0],0,0,0); \
      ACC[1] = __builtin_amdgcn_mfma_f32_16x16x32_bf16(WF[1][kc*4+j], hfa[j], ACC[1],0,0,0); \
    }                                                                             \
  }

#define PHASER(WF, HARR, ACC)                                                     \
  _Pragma("unroll") for (int ks = 0; ks < 8; ++ks){                               \
    ACC[0] = __builtin_amdgcn_mfma_f32_16x16x32_bf16(WF[0][ks], HARR[ks], ACC[0],0,0,0); \
    ACC[1] = __builtin_amdgcn_mfma_f32_16x16x32_bf16(WF[1][ks], HARR[ks], ACC[1],0,0,0); \
  }

#define TANH_PACK_STORE(ACC, WOFF, GSTORE, SPAR)                                  \
  _Pragma("unroll") for (int nt = 0; nt < 2; ++nt){                               \
    float t0 = tanh_fast(ACC[nt][0]), t1 = tanh_fast(ACC[nt][1]);                 \
    float t2 = tanh_fast(ACC[nt][2]), t3 = tanh_fast(ACC[nt][3]);                 \
    unsigned plo, phi;                                                            \
    asm("v_cvt_pk_bf16_f32 %0, %1, %2" : "=v"(plo) : "v"(t0), "v"(t1));           \
    asm("v_cvt_pk_bf16_f32 %0, %1, %2" : "=v"(phi) : "v"(t2), "v"(t3));           \
    uint2 p; p.x = plo; p.y = phi;                                                \
    *reinterpret_cast<uint2*>(ldsb + (WOFF) + woffb + nt*512) = p;                \
    if (GSTORE) *reinterpret_cast<uint2*>(hop + (SPAR)*NH + nt*16) = p;           \
  }

#define STEP(R0, W0, R1, W1, XS, IREG, SPAR)                                      \
  do {                                                                            \
    bf16x8 hC[8];                                                                 \
    _Pragma("unroll") for (int ks = 0; ks < 8; ++ks)                              \
      hC[ks] = *reinterpret_cast<const bf16x8*>(ldsb + (R1) + roffb + ks*1024);   \
    f32x4 acc0[2];                                                                \
    _Pragma("unroll") for (int nt = 0; nt < 2; ++nt)                              \
      _Pragma("unroll") for (int r = 0; r < 4; ++r)                               \
        acc0[nt][r] = bf2f(((const unsigned short*)&XS[nt])[r]);                  \
    { const unsigned short* gb = pre0b + (size_t)IREG*NH + cq;                    \
      XS[0] = *reinterpret_cast<const ushort4*>(gb);                              \
      XS[1] = *reinterpret_cast<const ushort4*>(gb + 16);                         \
      int sn = s + (SPAR) + 4; sn = (sn < NS) ? sn : NS - 1;                      \
      IREG = batch_g[sn]; }                                                       \
    PHASE(wf0, R0, acc0);                                                         \
    TANH_PACK_STORE(acc0, W0, 0, SPAR);                                           \
    BAR();                                                                        \
    f32x4 acc1[2]; acc1[0] = biasv[0]; acc1[1] = biasv[1];                        \
    PHASER(wf1, hC, acc1);                                                        \
    PHASE(wfG, W0, acc1);                                                         \
    TANH_PACK_STORE(acc1, W1, 1, SPAR);                                           \
    BAR();                                                                        \
  } while (0)

__global__ __launch_bounds__(512, 2) void k_rnn_fused(
        const int* __restrict__ batch,
        const unsigned short* __restrict__ pre0b,
        const __hip_bfloat16* __restrict__ Whh0,
        const __hip_bfloat16* __restrict__ Wih1,
        const __hip_bfloat16* __restrict__ Whh1,
        const __hip_bfloat16* __restrict__ bih1,
        const __hip_bfloat16* __restrict__ bhh1,
        __hip_bfloat16* __restrict__ hout){
    const int l  = threadIdx.x & 63;
    const int w  = threadIdx.x >> 6;   // 0..7
    const int b0 = blockIdx.x * 16;
    const int lr = l & 15;
    const int kq = l >> 4;
    const int c0 = w * 32;
    const int cq = c0 + kq*4;

    bf16x8 wf0[2][8], wfG[2][8], wf1[2][8];
#pragma unroll
    for (int nt = 0; nt < 2; ++nt)
#pragma unroll
        for (int ks = 0; ks < 8; ++ks){
            const size_t o = (size_t)(c0 + nt*16 + lr)*NH + ks*32 + kq*8;
            wf0[nt][ks] = *reinterpret_cast<const bf16x8*>(Whh0 + o);
            wfG[nt][ks] = *reinterpret_cast<const bf16x8*>(Wih1 + o);
            wf1[nt][ks] = *reinterpret_cast<const bf16x8*>(Whh1 + o);
            asm volatile("" : "+v"(wf0[nt][ks]));
            asm volatile("" : "+v"(wfG[nt][ks]));
            asm volatile("" : "+v"(wf1[nt][ks]));
        }

    f32x4 biasv[2];
#pragma unroll
    for (int nt = 0; nt < 2; ++nt)
#pragma unroll
        for (int r = 0; r < 4; ++r){
            int c = cq + nt*16 + r;
            biasv[nt][r] = __bfloat162float(bih1[c]) + __bfloat162float(bhh1[c]);
        }

    __shared__ __align__(16) char lds_all[32768];
    char* ldsb = lds_all;
    *reinterpret_cast<uint4*>(ldsb + threadIdx.x*16)         = uint4{0,0,0,0};
    *reinterpret_cast<uint4*>(ldsb + 16384 + threadIdx.x*16) = uint4{0,0,0,0};

    const int roffb = kq*256 + lr*16;
    const int woffb = (cq >> 3)*256 + lr*16 + (cq & 7)*2;

    const int* batch_g = batch + (size_t)(b0 + lr)*NS;
    __hip_bfloat16* hop = hout + ((size_t)(b0+lr)*NS)*NH + cq;

    ushort4 xA[2], xB[2]; int iA, iB;
    {
        int j0 = batch_g[0], j1 = batch_g[1];
        const unsigned short* g0 = pre0b + (size_t)j0*NH + cq;
        const unsigned short* g1 = pre0b + (size_t)j1*NH + cq;
        xA[0] = *reinterpret_cast<const ushort4*>(g0);
        xA[1] = *reinterpret_cast<const ushort4*>(g0 + 16);
        xB[0] = *reinterpret_cast<const ushort4*>(g1);
        xB[1] = *reinterpret_cast<const ushort4*>(g1 + 16);
        iA = batch_g[2]; iB = batch_g[3];
    }
    __syncthreads();

    for (int s = 0; s < NS; s += 2){
        STEP(0,    8192, 16384, 24576, xA, iA, 0);
        STEP(8192, 0,    24576, 16384, xB, iB, 1);
        hop += 2*NH;
    }
}

// ---------------------------------------------------------------------------
// K3: output GEMM, 256-row macro-tile per WG. C[M,1000] = A[M,256]@W^T + b.
// W-frags (64 cols x 256 k) loaded ONCE into 128 pinned VGPRs, reused for
// 4 m-subtiles.
// ---------------------------------------------------------------------------
template<int N>
__global__ __launch_bounds__(256, 2) void k_gemm_big(
        const __hip_bfloat16* __restrict__ A,
        const __hip_bfloat16* __restrict__ W,
        const __hip_bfloat16* __restrict__ bias,
        void* __restrict__ Cout, int ldc,
        const void* __restrict__ probe){
    const bool f32out = detect_f32(probe);
    const int m0 = blockIdx.x * 256;
    const int n0 = blockIdx.y * 64;
    const int wv = threadIdx.x >> 6;
    const int l  = threadIdx.x & 63;
    const int lr = l & 15;
    const int kb = (l >> 4) * 8;

    bf16x8 wfr[4][8];
#pragma unroll
    for (int nt = 0; nt < 4; ++nt){
        int ncol = n0 + nt*16 + lr;
        int nc = (ncol < N) ? ncol : (N-1);
#pragma unroll
        for (int ks = 0; ks < 8; ++ks){
            wfr[nt][ks] = *reinterpret_cast<const bf16x8*>(
                W + (size_t)nc*NH + ks*32 + kb);
            asm volatile("" : "+v"(wfr[nt][ks]));
        }
    }

    float bsum[4];
#pragma unroll
    for (int nt = 0; nt < 4; ++nt){
        int ncol = n0 + nt*16 + lr;
        bsum[nt] = (ncol < N) ? __bfloat162float(bias[ncol]) : 0.f;
    }

#pragma unroll
    for (int mt = 0; mt < 4; ++mt){
        const int mrow = m0 + mt*64 + wv*16 + lr;
        bf16x8 af[8];
#pragma unroll
        for (int ks = 0; ks < 8; ++ks)
            af[ks] = *reinterpret_cast<const bf16x8*>(
                A + (size_t)mrow*NH + ks*32 + kb);
        f32x4 acc[4] = {};
#pragma unroll
        for (int ks = 0; ks < 8; ++ks){
#pragma unroll
            for (int nt = 0; nt < 4; ++nt)
                acc[nt] = __builtin_amdgcn_mfma_f32_16x16x32_bf16(
                    af[ks], wfr[nt][ks], acc[nt], 0, 0, 0);
        }
#pragma unroll
        for (int nt = 0; nt < 4; ++nt){
            int ncol = n0 + nt*16 + lr;
            if (ncol >= N) continue;
#pragma unroll
            for (int r = 0; r < 4; ++r){
                int row = m0 + mt*64 + wv*16 + (l>>4)*4 + r;
                float val = acc[nt][r] + bsum[nt];
                if (f32out) ((float*)Cout)[(size_t)row*ldc + ncol] = val;
                else        ((__hip_bfloat16*)Cout)[(size_t)row*ldc + ncol] = __float2bfloat16(val);
            }
        }
    }
}

// ---------------------------------------------------------------------------
extern "C" void kernel_launch(void* const* d_in, const int* in_sizes, int n_in,
                              void* d_out, int out_size, void* d_ws, size_t ws_size,
                              hipStream_t stream){
    const int* batch = (const int*)d_in[0];
    const void* probe = d_in[3];  // raw W_hh0 for dtype detection

    char* ws = (char*)d_ws;
    size_t off = 0;
    auto give = [&](size_t bytes)->char*{
        char* p = ws + off; off = (off + bytes + 511) & ~(size_t)511; return p;
    };
    __hip_bfloat16* cFeats = (__hip_bfloat16*)give(2*NV*NF);
    __hip_bfloat16* cWih0  = (__hip_bfloat16*)give(2*NH*NF);
    __hip_bfloat16* cWhh0  = (__hip_bfloat16*)give(2*NH*NH);
    __hip_bfloat16* cBih0  = (__hip_bfloat16*)give(2*NH);
    __hip_bfloat16* cBhh0  = (__hip_bfloat16*)give(2*NH);
    __hip_bfloat16* cWih1  = (__hip_bfloat16*)give(2*NH*NH);
    __hip_bfloat16* cWhh1  = (__hip_bfloat16*)give(2*NH*NH);
    __hip_bfloat16* cBih1  = (__hip_bfloat16*)give(2*NH);
    __hip_bfloat16* cBhh1  = (__hip_bfloat16*)give(2*NH);
    __hip_bfloat16* cWout  = (__hip_bfloat16*)give(2*NV*NH);
    __hip_bfloat16* cBout  = (__hip_bfloat16*)give(2*NV);
    __hip_bfloat16* pre0b  = (__hip_bfloat16*)give(2*NV*NH + 64);
    __hip_bfloat16* hbuf   = (__hip_bfloat16*)give(2*(size_t)NB*NS*NH);

    ConvArgs ca;
    const void* srcs[11] = { d_in[1], d_in[2], d_in[3], d_in[4], d_in[5], d_in[6],
                             d_in[7], d_in[8], d_in[9], d_in[10], d_in[11] };
    __hip_bfloat16* dsts[11] = { cFeats, cWih0, cWhh0, cBih0, cBhh0, cWih1,
                                 cWhh1, cBih1, cBhh1, cWout, cBout };
    int ns[11] = { NV*NF, NH*NF, NH*NH, NH, NH, NH*NH, NH*NH, NH, NH, NV*NH, NV };
    for (int i = 0; i < 11; ++i){ ca.src[i] = srcs[i]; ca.dst[i] = dsts[i]; ca.n[i] = ns[i]; }
    k_conv_all<<<dim3(64, 11), dim3(256), 0, stream>>>(ca, probe);

    k_pre0<<<dim3(NV), dim3(256), 0, stream>>>(cFeats, cWih0, cBih0, cBhh0, pre0b);
    k_rnn_fused<<<dim3(NB/16), dim3(512), 0, stream>>>(
        batch, (const unsigned short*)pre0b, cWhh0, cWih1, cWhh1, cBih1, cBhh1, hbuf);
    k_gemm_big<NV><<<dim3((NB*NS)/256, 16), dim3(256), 0, stream>>>(
        hbuf, cWout, cBout, d_out, NV, probe);
}